// Round 1
// baseline (608.118 us; speedup 1.0000x reference)
//
#include <hip/hip_runtime.h>

#define NB 8
#define S 2048
#define D 128
#define BQ 32
#define BK 32
#define NKT (S / BK)   // 64
#define NQT (S / BQ)   // 64
#define INV_SQRT_D 0.08838834764831845f

// 2x2 register-blocked dot products over D=128 from LDS tiles
__device__ __forceinline__ void dot2x2(
    const float (*qs)[D + 4], const float (*ks)[D + 4],
    int r0, int c0, float& a00, float& a01, float& a10, float& a11)
{
    float s00 = 0.f, s01 = 0.f, s10 = 0.f, s11 = 0.f;
#pragma unroll 8
    for (int kk = 0; kk < D; kk += 4) {
        const float4 qa = *(const float4*)&qs[r0][kk];
        const float4 qb = *(const float4*)&qs[r0 + 1][kk];
        const float4 ka = *(const float4*)&ks[c0][kk];
        const float4 kb = *(const float4*)&ks[c0 + 1][kk];
        s00 = fmaf(qa.x, ka.x, s00); s00 = fmaf(qa.y, ka.y, s00);
        s00 = fmaf(qa.z, ka.z, s00); s00 = fmaf(qa.w, ka.w, s00);
        s01 = fmaf(qa.x, kb.x, s01); s01 = fmaf(qa.y, kb.y, s01);
        s01 = fmaf(qa.z, kb.z, s01); s01 = fmaf(qa.w, kb.w, s01);
        s10 = fmaf(qb.x, ka.x, s10); s10 = fmaf(qb.y, ka.y, s10);
        s10 = fmaf(qb.z, ka.z, s10); s10 = fmaf(qb.w, ka.w, s10);
        s11 = fmaf(qb.x, kb.x, s11); s11 = fmaf(qb.y, kb.y, s11);
        s11 = fmaf(qb.z, kb.z, s11); s11 = fmaf(qb.w, kb.w, s11);
    }
    a00 = s00; a01 = s01; a10 = s10; a11 = s11;
}

__device__ __forceinline__ void online_upd(bool cond, float s, float& m, float& l)
{
    if (cond) {
        if (s <= m) {
            l += __expf(s - m);
        } else {
            l = l * __expf(m - s) + 1.0f;
            m = s;
        }
    }
}

__global__ __launch_bounds__(256) void attn_kernel(
    const float* __restrict__ q,
    const float* __restrict__ k,
    const float* __restrict__ v,
    const float* __restrict__ rep,
    float* __restrict__ out,
    float* __restrict__ attn)
{
    __shared__ float qs[BQ][D + 4];
    __shared__ float ks[BK][D + 4];
    __shared__ float vs[BK][D + 4];
    __shared__ float ps[BQ][BK + 4];
    __shared__ float red_m[BQ][16];
    __shared__ float red_l[BQ][16];
    __shared__ float m_row[BQ];
    __shared__ float dinv_row[BQ];
    __shared__ float vq[BQ];
    __shared__ float vk[BK];

    const int tid = threadIdx.x;
    const int bid = blockIdx.x;
    const int b = bid & 7;                 // batch
    const int qt = (NQT - 1) - (bid >> 3); // heavy q-tiles dispatched first
    const int i0 = qt * BQ;

    // ---- load Q tile (32 x 128) + per-row validity ----
    for (int f = tid; f < BQ * D / 4; f += 256) {
        const int r = f >> 5, c4 = f & 31;
        *(float4*)&qs[r][c4 * 4] =
            *(const float4*)&q[((size_t)b * S + i0 + r) * D + c4 * 4];
    }
    if (tid < BQ) vq[tid] = rep[(size_t)b * S + i0 + tid];

    const int tr = tid >> 4;   // 0..15
    const int tc = tid & 15;   // 0..15
    const int r0 = tr * 2;
    const int c0 = tc * 2;

    // per-thread online softmax state for rows r0, r0+1
    // m init 0: replicates reference max over masked_vec (masked entries = 0)
    float m0 = 0.f, l0 = 0.f, m1 = 0.f, l1 = 0.f;

    // ================= phase A: row max + denom (online) =================
    for (int kt = 0; kt <= qt; ++kt) {
        __syncthreads();   // protect ks from previous iteration's readers
        for (int f = tid; f < BK * D / 4; f += 256) {
            const int r = f >> 5, c4 = f & 31;
            *(float4*)&ks[r][c4 * 4] =
                *(const float4*)&k[((size_t)b * S + kt * BK + r) * D + c4 * 4];
        }
        if (tid < BK) vk[tid] = rep[(size_t)b * S + kt * BK + tid];
        __syncthreads();

        float a00, a01, a10, a11;
        dot2x2(qs, ks, r0, c0, a00, a01, a10, a11);

        const int i_0 = i0 + r0, i_1 = i0 + r0 + 1;
        const int j_0 = kt * BK + c0, j_1 = kt * BK + c0 + 1;
        const bool vr0 = vq[r0] > 0.5f, vr1 = vq[r0 + 1] > 0.5f;
        const bool vc0 = vk[c0] > 0.5f, vc1 = vk[c0 + 1] > 0.5f;

        online_upd((j_0 < i_0) && vr0 && vc0, a00 * INV_SQRT_D - (float)(i_0 - j_0), m0, l0);
        online_upd((j_1 < i_0) && vr0 && vc1, a01 * INV_SQRT_D - (float)(i_0 - j_1), m0, l0);
        online_upd((j_0 < i_1) && vr1 && vc0, a10 * INV_SQRT_D - (float)(i_1 - j_0), m1, l1);
        online_upd((j_1 < i_1) && vr1 && vc1, a11 * INV_SQRT_D - (float)(i_1 - j_1), m1, l1);
    }

    // ---- merge (m,l) across the 16 threads of each row ----
    __syncthreads();
    red_m[r0][tc] = m0;     red_l[r0][tc] = l0;
    red_m[r0 + 1][tc] = m1; red_l[r0 + 1][tc] = l1;
    __syncthreads();
    if (tid < BQ) {
        float m = red_m[tid][0], l = red_l[tid][0];
#pragma unroll
        for (int t = 1; t < 16; ++t) {
            const float m2 = red_m[tid][t], l2 = red_l[tid][t];
            const float mn = fmaxf(m, m2);
            l = l * __expf(m - mn) + l2 * __expf(m2 - mn);
            m = mn;
        }
        // reference: sums += (sums==0); attn = exps / (sums + 1e-20)
        const float denom = l + ((l == 0.0f) ? 1.0f : 0.0f) + 1e-20f;
        m_row[tid] = m;
        dinv_row[tid] = 1.0f / denom;
    }
    __syncthreads();

    // ================= phase B: recompute, write attn, PV =================
    const int pr = tid >> 3;       // 0..31 row
    const int pc4 = tid & 7;       // float4 group within 32-col tile
    const int cb = pc4 * 16;       // 16 output cols per thread for PV

    float o[16];
#pragma unroll
    for (int x = 0; x < 16; ++x) o[x] = 0.f;

    for (int kt = 0; kt < NKT; ++kt) {
        if (kt <= qt) {
            __syncthreads();   // protect ks/vs/ps from previous readers
            for (int f = tid; f < BK * D / 4; f += 256) {
                const int r = f >> 5, c4 = f & 31;
                *(float4*)&ks[r][c4 * 4] =
                    *(const float4*)&k[((size_t)b * S + kt * BK + r) * D + c4 * 4];
                *(float4*)&vs[r][c4 * 4] =
                    *(const float4*)&v[((size_t)b * S + kt * BK + r) * D + c4 * 4];
            }
            if (tid < BK) vk[tid] = rep[(size_t)b * S + kt * BK + tid];
            __syncthreads();

            float a00, a01, a10, a11;
            dot2x2(qs, ks, r0, c0, a00, a01, a10, a11);

            const int i_0 = i0 + r0, i_1 = i0 + r0 + 1;
            const int j_0 = kt * BK + c0, j_1 = kt * BK + c0 + 1;
            const bool vr0 = vq[r0] > 0.5f, vr1 = vq[r0 + 1] > 0.5f;
            const bool vc0 = vk[c0] > 0.5f, vc1 = vk[c0 + 1] > 0.5f;

            float p00 = 0.f, p01 = 0.f, p10 = 0.f, p11 = 0.f;
            if ((j_0 < i_0) && vr0 && vc0)
                p00 = __expf(a00 * INV_SQRT_D - (float)(i_0 - j_0) - m_row[r0]) * dinv_row[r0];
            if ((j_1 < i_0) && vr0 && vc1)
                p01 = __expf(a01 * INV_SQRT_D - (float)(i_0 - j_1) - m_row[r0]) * dinv_row[r0];
            if ((j_0 < i_1) && vr1 && vc0)
                p10 = __expf(a10 * INV_SQRT_D - (float)(i_1 - j_0) - m_row[r0 + 1]) * dinv_row[r0 + 1];
            if ((j_1 < i_1) && vr1 && vc1)
                p11 = __expf(a11 * INV_SQRT_D - (float)(i_1 - j_1) - m_row[r0 + 1]) * dinv_row[r0 + 1];

            ps[r0][c0] = p00;     ps[r0][c0 + 1] = p01;
            ps[r0 + 1][c0] = p10; ps[r0 + 1][c0 + 1] = p11;
            __syncthreads();

            // write attn tile (final normalized values)
            *(float4*)&attn[((size_t)b * S + i0 + pr) * S + kt * BK + pc4 * 4] =
                *(const float4*)&ps[pr][pc4 * 4];

            // PV: o[pr][cb..cb+15] += ps[pr][:] @ vs[:][cb..cb+15]
            for (int kk = 0; kk < BK; ++kk) {
                const float pval = ps[pr][kk];
                const float4 v0 = *(const float4*)&vs[kk][cb];
                const float4 v1 = *(const float4*)&vs[kk][cb + 4];
                const float4 v2 = *(const float4*)&vs[kk][cb + 8];
                const float4 v3 = *(const float4*)&vs[kk][cb + 12];
                o[0]  = fmaf(pval, v0.x, o[0]);  o[1]  = fmaf(pval, v0.y, o[1]);
                o[2]  = fmaf(pval, v0.z, o[2]);  o[3]  = fmaf(pval, v0.w, o[3]);
                o[4]  = fmaf(pval, v1.x, o[4]);  o[5]  = fmaf(pval, v1.y, o[5]);
                o[6]  = fmaf(pval, v1.z, o[6]);  o[7]  = fmaf(pval, v1.w, o[7]);
                o[8]  = fmaf(pval, v2.x, o[8]);  o[9]  = fmaf(pval, v2.y, o[9]);
                o[10] = fmaf(pval, v2.z, o[10]); o[11] = fmaf(pval, v2.w, o[11]);
                o[12] = fmaf(pval, v3.x, o[12]); o[13] = fmaf(pval, v3.y, o[13]);
                o[14] = fmaf(pval, v3.z, o[14]); o[15] = fmaf(pval, v3.w, o[15]);
            }
        } else {
            // strictly above the causal block-diagonal: attn = 0
            const float4 z = make_float4(0.f, 0.f, 0.f, 0.f);
            *(float4*)&attn[((size_t)b * S + i0 + pr) * S + kt * BK + pc4 * 4] = z;
        }
    }

    // ---- write out tile ----
#pragma unroll
    for (int x = 0; x < 4; ++x) {
        const float4 t = make_float4(o[x * 4], o[x * 4 + 1], o[x * 4 + 2], o[x * 4 + 3]);
        *(float4*)&out[((size_t)b * S + i0 + pr) * D + cb + x * 4] = t;
    }
}

extern "C" void kernel_launch(void* const* d_in, const int* in_sizes, int n_in,
                              void* d_out, int out_size, void* d_ws, size_t ws_size,
                              hipStream_t stream)
{
    const float* q   = (const float*)d_in[0];
    const float* k   = (const float*)d_in[1];
    const float* v   = (const float*)d_in[2];
    const float* rep = (const float*)d_in[3];
    float* out  = (float*)d_out;
    float* attn = out + (size_t)NB * S * D;

    hipLaunchKernelGGL(attn_kernel, dim3(NB * NQT), dim3(256), 0, stream,
                       q, k, v, rep, out, attn);
}

// Round 2
// 147.614 us; speedup vs baseline: 4.1197x; 4.1197x over previous
//
#include <hip/hip_runtime.h>

#define NBATCH 8
#define S 2048
#define D 128
#define BQ 32
#define BK 64
#define NKT (S / BK)   // 32
#define NQT (S / BQ)   // 64
#define INV_SQRT_D 0.08838834764831845f

typedef __bf16 bfv8 __attribute__((ext_vector_type(8)));
typedef float f32x4 __attribute__((ext_vector_type(4)));

__device__ __forceinline__ f32x4 mfma16(bfv8 a, bfv8 b, f32x4 c) {
    return __builtin_amdgcn_mfma_f32_16x16x32_bf16(a, b, c, 0, 0, 0);
}

__device__ __forceinline__ unsigned int pack2(float lo, float hi) {
    unsigned short a = __builtin_bit_cast(unsigned short, (__bf16)lo);
    unsigned short b = __builtin_bit_cast(unsigned short, (__bf16)hi);
    return (unsigned int)a | ((unsigned int)b << 16);
}

__global__ __launch_bounds__(256) void attn_kernel(
    const float* __restrict__ q,
    const float* __restrict__ k,
    const float* __restrict__ v,
    const float* __restrict__ rep,
    float* __restrict__ out,
    float* __restrict__ attn)
{
    // padded LDS tiles: frag reads are 2-way bank aliased (free on CDNA4)
    __shared__ __attribute__((aligned(16))) __bf16 qs [BQ][136];  // 32x128 + 8 pad
    __shared__ __attribute__((aligned(16))) __bf16 ksm[BK][136];  // 64x128 + 8 pad
    __shared__ __attribute__((aligned(16))) __bf16 vsT[D][72];    // V transposed: [d][kv], 64 + 8 pad
    __shared__ __attribute__((aligned(16))) __bf16 ps [BQ][72];   // P tile bf16
    __shared__ float redsum[2][2][16];
    __shared__ float dinv_lds[BQ];

    const int tid  = threadIdx.x;
    const int bid  = blockIdx.x;
    const int b    = bid & 7;
    const int qt   = (NQT - 1) - (bid >> 3);   // heavy q-tiles first
    const int i0   = qt * BQ;
    const int NT   = ((qt * BQ + (BQ - 2)) >> 6) + 1;  // k-tiles with any j < i

    const int lane = tid & 63;
    const int w    = tid >> 6;     // wave 0..3
    const int rg   = w >> 1;       // q row-group (0/1): rows rg*16..+15
    const int ch   = w & 1;        // kv col-half in QK / d-half in PV
    const int lr   = lane & 15;
    const int lg   = lane >> 4;    // 0..3

    // ---- stage Q tile -> bf16 LDS ----
    for (int c = tid; c < BQ * 16; c += 256) {
        const int row = c >> 4, c8 = c & 15;
        const float4 f0 = *(const float4*)&q[((size_t)(b * S + i0 + row)) * D + c8 * 8];
        const float4 f1 = *(const float4*)&q[((size_t)(b * S + i0 + row)) * D + c8 * 8 + 4];
        bfv8 t;
        t[0] = (__bf16)f0.x; t[1] = (__bf16)f0.y; t[2] = (__bf16)f0.z; t[3] = (__bf16)f0.w;
        t[4] = (__bf16)f1.x; t[5] = (__bf16)f1.y; t[6] = (__bf16)f1.z; t[7] = (__bf16)f1.w;
        *(bfv8*)&qs[row][c8 * 8] = t;
    }
    __syncthreads();

    // ---- hoist Q fragments to registers (A-frag: row=lr, k contiguous 8 at lg*8) ----
    bfv8 qa[4];
#pragma unroll
    for (int ks = 0; ks < 4; ++ks)
        qa[ks] = *(const bfv8*)&qs[rg * 16 + lr][ks * 32 + lg * 8];

    // per-lane q-row indices + validity
    int  i_r[4];
    bool bi[4];
#pragma unroll
    for (int r = 0; r < 4; ++r) {
        i_r[r] = i0 + rg * 16 + lg * 4 + r;
        bi[r]  = rep[(size_t)b * S + i_r[r]] > 0.5f;
    }

    // ================= pass A: masked row sums of exp(s) =================
    float lsum[4] = {0.f, 0.f, 0.f, 0.f};

    for (int kt = 0; kt < NT; ++kt) {
        __syncthreads();
        for (int c = tid; c < BK * 16; c += 256) {
            const int row = c >> 4, c8 = c & 15;
            const float4 f0 = *(const float4*)&k[((size_t)(b * S + kt * BK + row)) * D + c8 * 8];
            const float4 f1 = *(const float4*)&k[((size_t)(b * S + kt * BK + row)) * D + c8 * 8 + 4];
            bfv8 t;
            t[0] = (__bf16)f0.x; t[1] = (__bf16)f0.y; t[2] = (__bf16)f0.z; t[3] = (__bf16)f0.w;
            t[4] = (__bf16)f1.x; t[5] = (__bf16)f1.y; t[6] = (__bf16)f1.z; t[7] = (__bf16)f1.w;
            *(bfv8*)&ksm[row][c8 * 8] = t;
        }
        __syncthreads();

        f32x4 acc0 = {0.f, 0.f, 0.f, 0.f}, acc1 = {0.f, 0.f, 0.f, 0.f};
#pragma unroll
        for (int ks = 0; ks < 4; ++ks) {
            const bfv8 b0 = *(const bfv8*)&ksm[ch * 32 + lr][ks * 32 + lg * 8];
            const bfv8 b1 = *(const bfv8*)&ksm[ch * 32 + 16 + lr][ks * 32 + lg * 8];
            acc0 = mfma16(qa[ks], b0, acc0);
            acc1 = mfma16(qa[ks], b1, acc1);
        }

        const int j0 = kt * BK + ch * 32 + lr;
        const int j1 = j0 + 16;
        const bool vj0 = rep[(size_t)b * S + j0] > 0.5f;
        const bool vj1 = rep[(size_t)b * S + j1] > 0.5f;
#pragma unroll
        for (int r = 0; r < 4; ++r) {
            const int i = i_r[r];
            const float p0 = (bi[r] && vj0 && (j0 < i))
                ? __expf(acc0[r] * INV_SQRT_D - (float)(i - j0)) : 0.f;
            const float p1 = (bi[r] && vj1 && (j1 < i))
                ? __expf(acc1[r] * INV_SQRT_D - (float)(i - j1)) : 0.f;
            lsum[r] += p0 + p1;
        }
    }

    // ---- reduce row sums: 16 lanes (cols) -> cross wave-half ----
#pragma unroll
    for (int r = 0; r < 4; ++r) {
        lsum[r] += __shfl_xor(lsum[r], 1);
        lsum[r] += __shfl_xor(lsum[r], 2);
        lsum[r] += __shfl_xor(lsum[r], 4);
        lsum[r] += __shfl_xor(lsum[r], 8);
    }
    if (lr == 0) {
#pragma unroll
        for (int r = 0; r < 4; ++r) redsum[rg][ch][lg * 4 + r] = lsum[r];
    }
    __syncthreads();
    if (tid < BQ) {
        const float s = redsum[tid >> 4][0][tid & 15] + redsum[tid >> 4][1][tid & 15];
        dinv_lds[tid] = 1.f / (s + ((s == 0.f) ? 1.f : 0.f) + 1e-20f);
    }
    __syncthreads();

    float dinv[4];
#pragma unroll
    for (int r = 0; r < 4; ++r) dinv[r] = dinv_lds[rg * 16 + lg * 4 + r];

    // ================= pass B: recompute, write attn, PV =================
    f32x4 oacc[4];
#pragma unroll
    for (int nf = 0; nf < 4; ++nf) oacc[nf] = (f32x4){0.f, 0.f, 0.f, 0.f};

    for (int kt = 0; kt < NT; ++kt) {
        __syncthreads();
        // stage K (row-major bf16)
        for (int c = tid; c < BK * 16; c += 256) {
            const int row = c >> 4, c8 = c & 15;
            const float4 f0 = *(const float4*)&k[((size_t)(b * S + kt * BK + row)) * D + c8 * 8];
            const float4 f1 = *(const float4*)&k[((size_t)(b * S + kt * BK + row)) * D + c8 * 8 + 4];
            bfv8 t;
            t[0] = (__bf16)f0.x; t[1] = (__bf16)f0.y; t[2] = (__bf16)f0.z; t[3] = (__bf16)f0.w;
            t[4] = (__bf16)f1.x; t[5] = (__bf16)f1.y; t[6] = (__bf16)f1.z; t[7] = (__bf16)f1.w;
            *(bfv8*)&ksm[row][c8 * 8] = t;
        }
        // stage V transposed: vsT[d][kv]; lane spans kv-pair -> conflict-free LDS writes
        for (int u = tid; u < 1024; u += 256) {
            const int p  = u & 31;          // kv pair
            const int dq = u >> 5;          // d quad
            const float4 va = *(const float4*)&v[((size_t)(b * S + kt * BK + 2 * p)) * D + dq * 4];
            const float4 vb = *(const float4*)&v[((size_t)(b * S + kt * BK + 2 * p + 1)) * D + dq * 4];
            *(unsigned int*)&vsT[dq * 4 + 0][2 * p] = pack2(va.x, vb.x);
            *(unsigned int*)&vsT[dq * 4 + 1][2 * p] = pack2(va.y, vb.y);
            *(unsigned int*)&vsT[dq * 4 + 2][2 * p] = pack2(va.z, vb.z);
            *(unsigned int*)&vsT[dq * 4 + 3][2 * p] = pack2(va.w, vb.w);
        }
        __syncthreads();

        f32x4 acc0 = {0.f, 0.f, 0.f, 0.f}, acc1 = {0.f, 0.f, 0.f, 0.f};
#pragma unroll
        for (int ks = 0; ks < 4; ++ks) {
            const bfv8 b0 = *(const bfv8*)&ksm[ch * 32 + lr][ks * 32 + lg * 8];
            const bfv8 b1 = *(const bfv8*)&ksm[ch * 32 + 16 + lr][ks * 32 + lg * 8];
            acc0 = mfma16(qa[ks], b0, acc0);
            acc1 = mfma16(qa[ks], b1, acc1);
        }

        const int j0 = kt * BK + ch * 32 + lr;
        const int j1 = j0 + 16;
        const bool vj0 = rep[(size_t)b * S + j0] > 0.5f;
        const bool vj1 = rep[(size_t)b * S + j1] > 0.5f;
#pragma unroll
        for (int r = 0; r < 4; ++r) {
            const int i = i_r[r];
            const float p0 = (bi[r] && vj0 && (j0 < i))
                ? __expf(acc0[r] * INV_SQRT_D - (float)(i - j0)) * dinv[r] : 0.f;
            const float p1 = (bi[r] && vj1 && (j1 < i))
                ? __expf(acc1[r] * INV_SQRT_D - (float)(i - j1)) * dinv[r] : 0.f;
            attn[((size_t)(b * S + i)) * S + j0] = p0;
            attn[((size_t)(b * S + i)) * S + j1] = p1;
            ps[rg * 16 + lg * 4 + r][ch * 32 + lr]      = (__bf16)p0;
            ps[rg * 16 + lg * 4 + r][ch * 32 + 16 + lr] = (__bf16)p1;
        }
        __syncthreads();

        // PV: O[q][d] += P[q][kv] * V[kv][d]; wave covers d-half ch*64..+63
#pragma unroll
        for (int ks = 0; ks < 2; ++ks) {
            const bfv8 pa = *(const bfv8*)&ps[rg * 16 + lr][ks * 32 + lg * 8];
#pragma unroll
            for (int nf = 0; nf < 4; ++nf) {
                const bfv8 vf = *(const bfv8*)&vsT[ch * 64 + nf * 16 + lr][ks * 32 + lg * 8];
                oacc[nf] = mfma16(pa, vf, oacc[nf]);
            }
        }
    }

    // ---- write out ----
#pragma unroll
    for (int nf = 0; nf < 4; ++nf)
#pragma unroll
        for (int r = 0; r < 4; ++r)
            out[((size_t)(b * S + i_r[r])) * D + ch * 64 + nf * 16 + lr] = oacc[nf][r];

    // ---- zero-fill attn tiles strictly above the block diagonal ----
    const int zt = NKT - NT;
    const float4 z4 = make_float4(0.f, 0.f, 0.f, 0.f);
    for (int u = tid; u < zt * 512; u += 256) {
        const int t   = u >> 9;
        const int rem = u & 511;
        const int row = rem >> 4;
        const int c4  = rem & 15;
        *(float4*)&attn[((size_t)(b * S + i0 + row)) * S + (NT + t) * BK + c4 * 4] = z4;
    }
}

extern "C" void kernel_launch(void* const* d_in, const int* in_sizes, int n_in,
                              void* d_out, int out_size, void* d_ws, size_t ws_size,
                              hipStream_t stream)
{
    const float* q   = (const float*)d_in[0];
    const float* k   = (const float*)d_in[1];
    const float* v   = (const float*)d_in[2];
    const float* rep = (const float*)d_in[3];
    float* out  = (float*)d_out;
    float* attn = out + (size_t)NBATCH * S * D;

    hipLaunchKernelGGL(attn_kernel, dim3(NBATCH * NQT), dim3(256), 0, stream,
                       q, k, v, rep, out, attn);
}

// Round 3
// 145.689 us; speedup vs baseline: 4.1741x; 1.0132x over previous
//
#include <hip/hip_runtime.h>

#define NBATCH 8
#define S 2048
#define D 128
#define BQ 32
#define BK 64
#define NKT (S / BK)   // 32
#define NQT (S / BQ)   // 64
#define INV_SQRT_D 0.08838834764831845f

typedef __bf16 bfv8 __attribute__((ext_vector_type(8)));
typedef float f32x4 __attribute__((ext_vector_type(4)));

__device__ __forceinline__ f32x4 mfma16(bfv8 a, bfv8 b, f32x4 c) {
    return __builtin_amdgcn_mfma_f32_16x16x32_bf16(a, b, c, 0, 0, 0);
}

__device__ __forceinline__ unsigned int pack2(float lo, float hi) {
    unsigned short a = __builtin_bit_cast(unsigned short, (__bf16)lo);
    unsigned short b = __builtin_bit_cast(unsigned short, (__bf16)hi);
    return (unsigned int)a | ((unsigned int)b << 16);
}

__global__ __launch_bounds__(256) void attn_kernel(
    const float* __restrict__ q,
    const float* __restrict__ k,
    const float* __restrict__ v,
    const float* __restrict__ rep,
    float* __restrict__ out,
    float* __restrict__ attn)
{
    // padded LDS tiles: frag reads are 2-way bank aliased (free on CDNA4)
    __shared__ __attribute__((aligned(16))) __bf16 qs [BQ][136];  // 32x128 + 8 pad
    __shared__ __attribute__((aligned(16))) __bf16 ksm[BK][136];  // 64x128 + 8 pad
    __shared__ __attribute__((aligned(16))) __bf16 vsT[D][72];    // V transposed: [d][kv], 64 + 8 pad
    __shared__ __attribute__((aligned(16))) __bf16 ps [BQ][72];   // P tile bf16
    __shared__ float redsum[2][2][16];
    __shared__ float dinv_lds[BQ];

    const int tid  = threadIdx.x;
    const int bid  = blockIdx.x;
    const int b    = bid & 7;
    const int qt   = (NQT - 1) - (bid >> 3);   // heavy q-tiles first
    const int i0   = qt * BQ;
    const int NT   = ((qt * BQ + (BQ - 2)) >> 6) + 1;  // k-tiles with any j < i

    const int lane = tid & 63;
    const int w    = tid >> 6;     // wave 0..3
    const int rg   = w >> 1;       // q row-group (0/1): rows rg*16..+15
    const int ch   = w & 1;        // kv col-half in QK / d-half in PV
    const int lr   = lane & 15;
    const int lg   = lane >> 4;    // 0..3

    // ---- stage Q tile -> bf16 LDS ----
    for (int c = tid; c < BQ * 16; c += 256) {
        const int row = c >> 4, c8 = c & 15;
        const float4 f0 = *(const float4*)&q[((size_t)(b * S + i0 + row)) * D + c8 * 8];
        const float4 f1 = *(const float4*)&q[((size_t)(b * S + i0 + row)) * D + c8 * 8 + 4];
        bfv8 t;
        t[0] = (__bf16)f0.x; t[1] = (__bf16)f0.y; t[2] = (__bf16)f0.z; t[3] = (__bf16)f0.w;
        t[4] = (__bf16)f1.x; t[5] = (__bf16)f1.y; t[6] = (__bf16)f1.z; t[7] = (__bf16)f1.w;
        *(bfv8*)&qs[row][c8 * 8] = t;
    }
    __syncthreads();

    // ---- hoist Q fragments to registers (A-frag: row=lr, k contiguous 8 at lg*8) ----
    bfv8 qa[4];
#pragma unroll
    for (int ks = 0; ks < 4; ++ks)
        qa[ks] = *(const bfv8*)&qs[rg * 16 + lr][ks * 32 + lg * 8];

    // per-lane q-row indices + validity
    int  i_r[4];
    bool bi[4];
#pragma unroll
    for (int r = 0; r < 4; ++r) {
        i_r[r] = i0 + rg * 16 + lg * 4 + r;
        bi[r]  = rep[(size_t)b * S + i_r[r]] > 0.5f;
    }

    // ================= pass A: masked row sums of exp(s) =================
    float lsum[4] = {0.f, 0.f, 0.f, 0.f};

    for (int kt = 0; kt < NT; ++kt) {
        __syncthreads();
        for (int c = tid; c < BK * 16; c += 256) {
            const int row = c >> 4, c8 = c & 15;
            const float4 f0 = *(const float4*)&k[((size_t)(b * S + kt * BK + row)) * D + c8 * 8];
            const float4 f1 = *(const float4*)&k[((size_t)(b * S + kt * BK + row)) * D + c8 * 8 + 4];
            bfv8 t;
            t[0] = (__bf16)f0.x; t[1] = (__bf16)f0.y; t[2] = (__bf16)f0.z; t[3] = (__bf16)f0.w;
            t[4] = (__bf16)f1.x; t[5] = (__bf16)f1.y; t[6] = (__bf16)f1.z; t[7] = (__bf16)f1.w;
            *(bfv8*)&ksm[row][c8 * 8] = t;
        }
        __syncthreads();

        f32x4 acc0 = {0.f, 0.f, 0.f, 0.f}, acc1 = {0.f, 0.f, 0.f, 0.f};
#pragma unroll
        for (int ks = 0; ks < 4; ++ks) {
            const bfv8 b0 = *(const bfv8*)&ksm[ch * 32 + lr][ks * 32 + lg * 8];
            const bfv8 b1 = *(const bfv8*)&ksm[ch * 32 + 16 + lr][ks * 32 + lg * 8];
            acc0 = mfma16(qa[ks], b0, acc0);
            acc1 = mfma16(qa[ks], b1, acc1);
        }

        const int j0 = kt * BK + ch * 32 + lr;
        const int j1 = j0 + 16;
        const bool vj0 = rep[(size_t)b * S + j0] > 0.5f;
        const bool vj1 = rep[(size_t)b * S + j1] > 0.5f;
#pragma unroll
        for (int r = 0; r < 4; ++r) {
            const int i = i_r[r];
            const float p0 = (bi[r] && vj0 && (j0 < i))
                ? __expf(acc0[r] * INV_SQRT_D - (float)(i - j0)) : 0.f;
            const float p1 = (bi[r] && vj1 && (j1 < i))
                ? __expf(acc1[r] * INV_SQRT_D - (float)(i - j1)) : 0.f;
            lsum[r] += p0 + p1;
        }
    }

    // ---- reduce row sums: 16 lanes (cols) -> cross wave-half ----
#pragma unroll
    for (int r = 0; r < 4; ++r) {
        lsum[r] += __shfl_xor(lsum[r], 1);
        lsum[r] += __shfl_xor(lsum[r], 2);
        lsum[r] += __shfl_xor(lsum[r], 4);
        lsum[r] += __shfl_xor(lsum[r], 8);
    }
    if (lr == 0) {
#pragma unroll
        for (int r = 0; r < 4; ++r) redsum[rg][ch][lg * 4 + r] = lsum[r];
    }
    __syncthreads();
    if (tid < BQ) {
        const float s = redsum[tid >> 4][0][tid & 15] + redsum[tid >> 4][1][tid & 15];
        dinv_lds[tid] = 1.f / (s + ((s == 0.f) ? 1.f : 0.f) + 1e-20f);
    }
    __syncthreads();

    float dinv[4];
#pragma unroll
    for (int r = 0; r < 4; ++r) dinv[r] = dinv_lds[rg * 16 + lg * 4 + r];

    // ================= pass B: recompute, write attn, PV =================
    f32x4 oacc[4];
#pragma unroll
    for (int nf = 0; nf < 4; ++nf) oacc[nf] = (f32x4){0.f, 0.f, 0.f, 0.f};

    for (int kt = 0; kt < NT; ++kt) {
        __syncthreads();
        // stage K (row-major bf16)
        for (int c = tid; c < BK * 16; c += 256) {
            const int row = c >> 4, c8 = c & 15;
            const float4 f0 = *(const float4*)&k[((size_t)(b * S + kt * BK + row)) * D + c8 * 8];
            const float4 f1 = *(const float4*)&k[((size_t)(b * S + kt * BK + row)) * D + c8 * 8 + 4];
            bfv8 t;
            t[0] = (__bf16)f0.x; t[1] = (__bf16)f0.y; t[2] = (__bf16)f0.z; t[3] = (__bf16)f0.w;
            t[4] = (__bf16)f1.x; t[5] = (__bf16)f1.y; t[6] = (__bf16)f1.z; t[7] = (__bf16)f1.w;
            *(bfv8*)&ksm[row][c8 * 8] = t;
        }
        // stage V transposed: vsT[d][kv]; lane spans kv-pair -> conflict-free LDS writes
        for (int u = tid; u < 1024; u += 256) {
            const int p  = u & 31;          // kv pair
            const int dq = u >> 5;          // d quad
            const float4 va = *(const float4*)&v[((size_t)(b * S + kt * BK + 2 * p)) * D + dq * 4];
            const float4 vb = *(const float4*)&v[((size_t)(b * S + kt * BK + 2 * p + 1)) * D + dq * 4];
            *(unsigned int*)&vsT[dq * 4 + 0][2 * p] = pack2(va.x, vb.x);
            *(unsigned int*)&vsT[dq * 4 + 1][2 * p] = pack2(va.y, vb.y);
            *(unsigned int*)&vsT[dq * 4 + 2][2 * p] = pack2(va.z, vb.z);
            *(unsigned int*)&vsT[dq * 4 + 3][2 * p] = pack2(va.w, vb.w);
        }
        __syncthreads();

        f32x4 acc0 = {0.f, 0.f, 0.f, 0.f}, acc1 = {0.f, 0.f, 0.f, 0.f};
#pragma unroll
        for (int ks = 0; ks < 4; ++ks) {
            const bfv8 b0 = *(const bfv8*)&ksm[ch * 32 + lr][ks * 32 + lg * 8];
            const bfv8 b1 = *(const bfv8*)&ksm[ch * 32 + 16 + lr][ks * 32 + lg * 8];
            acc0 = mfma16(qa[ks], b0, acc0);
            acc1 = mfma16(qa[ks], b1, acc1);
        }

        const int j0 = kt * BK + ch * 32 + lr;
        const int j1 = j0 + 16;
        const bool vj0 = rep[(size_t)b * S + j0] > 0.5f;
        const bool vj1 = rep[(size_t)b * S + j1] > 0.5f;
#pragma unroll
        for (int r = 0; r < 4; ++r) {
            const int i = i_r[r];
            const float p0 = (bi[r] && vj0 && (j0 < i))
                ? __expf(acc0[r] * INV_SQRT_D - (float)(i - j0)) * dinv[r] : 0.f;
            const float p1 = (bi[r] && vj1 && (j1 < i))
                ? __expf(acc1[r] * INV_SQRT_D - (float)(i - j1)) * dinv[r] : 0.f;
            attn[((size_t)(b * S + i)) * S + j0] = p0;
            attn[((size_t)(b * S + i)) * S + j1] = p1;
            ps[rg * 16 + lg * 4 + r][ch * 32 + lr]      = (__bf16)p0;
            ps[rg * 16 + lg * 4 + r][ch * 32 + 16 + lr] = (__bf16)p1;
        }
        __syncthreads();

        // PV: O[q][d] += P[q][kv] * V[kv][d]; wave covers d-half ch*64..+63
#pragma unroll
        for (int ks = 0; ks < 2; ++ks) {
            const bfv8 pa = *(const bfv8*)&ps[rg * 16 + lr][ks * 32 + lg * 8];
#pragma unroll
            for (int nf = 0; nf < 4; ++nf) {
                const bfv8 vf = *(const bfv8*)&vsT[ch * 64 + nf * 16 + lr][ks * 32 + lg * 8];
                oacc[nf] = mfma16(pa, vf, oacc[nf]);
            }
        }
    }

    // ---- write out ----
#pragma unroll
    for (int nf = 0; nf < 4; ++nf)
#pragma unroll
        for (int r = 0; r < 4; ++r)
            out[((size_t)(b * S + i_r[r])) * D + ch * 64 + nf * 16 + lr] = oacc[nf][r];

    // ---- zero-fill attn tiles strictly above the block diagonal ----
    const int zt = NKT - NT;
    const float4 z4 = make_float4(0.f, 0.f, 0.f, 0.f);
    for (int u = tid; u < zt * 512; u += 256) {
        const int t   = u >> 9;
        const int rem = u & 511;
        const int row = rem >> 4;
        const int c4  = rem & 15;
        *(float4*)&attn[((size_t)(b * S + i0 + row)) * S + (NT + t) * BK + c4 * 4] = z4;
    }
}

extern "C" void kernel_launch(void* const* d_in, const int* in_sizes, int n_in,
                              void* d_out, int out_size, void* d_ws, size_t ws_size,
                              hipStream_t stream)
{
    const float* q   = (const float*)d_in[0];
    const float* k   = (const float*)d_in[1];
    const float* v   = (const float*)d_in[2];
    const float* rep = (const float*)d_in[3];
    float* out  = (float*)d_out;
    float* attn = out + (size_t)NBATCH * S * D;

    hipLaunchKernelGGL(attn_kernel, dim3(NBATCH * NQT), dim3(256), 0, stream,
                       q, k, v, rep, out, attn);
}

// Round 4
// 78.779 us; speedup vs baseline: 7.7193x; 1.8493x over previous
//
#include <hip/hip_runtime.h>

#define NBATCH 8
#define S 2048
#define D 128
#define BQ 32
#define BK 64
#define NKT 32
#define NQT 64
#define INV_SQRT_D 0.08838834764831845f

typedef __bf16 bfv8 __attribute__((ext_vector_type(8)));
typedef float f32x4 __attribute__((ext_vector_type(4)));

__device__ __forceinline__ f32x4 mfma16(bfv8 a, bfv8 b, f32x4 c) {
    return __builtin_amdgcn_mfma_f32_16x16x32_bf16(a, b, c, 0, 0, 0);
}

__device__ __forceinline__ unsigned int pack2(float lo, float hi) {
    unsigned short a = __builtin_bit_cast(unsigned short, (__bf16)lo);
    unsigned short b = __builtin_bit_cast(unsigned short, (__bf16)hi);
    return (unsigned int)a | ((unsigned int)b << 16);
}

__device__ __forceinline__ void gload_lds16(const void* g, void* l) {
    __builtin_amdgcn_global_load_lds(
        (const __attribute__((address_space(1))) unsigned int*)g,
        (__attribute__((address_space(3))) unsigned int*)l, 16, 0, 0);
}

// ============ prep: K -> bf16 swizzled tiles; V -> bf16 transposed swizzled ============
// kb tile (b,kt): 64 rows x 16 units(16B, 8 bf16 of d); unit stored at u^(row&7)
// vtb tile (b,kt): 128 d-rows x 8 units(8 bf16 of kv); unit stored at u^(d&7)
__global__ __launch_bounds__(256) void prep_kernel(
    const float* __restrict__ k, const float* __restrict__ v,
    __bf16* __restrict__ kb, __bf16* __restrict__ vtb)
{
    const int t = blockIdx.x * 256 + threadIdx.x;
    if (t < 262144) {              // K part: 8*32*64*16 units
        const int b   = t >> 15;
        const int kt  = (t >> 10) & 31;
        const int row = (t >> 4) & 63;
        const int u   = t & 15;
        const float4 f0 = *(const float4*)&k[((size_t)(b * S + kt * 64 + row)) * D + u * 8];
        const float4 f1 = *(const float4*)&k[((size_t)(b * S + kt * 64 + row)) * D + u * 8 + 4];
        bfv8 o;
        o[0] = (__bf16)f0.x; o[1] = (__bf16)f0.y; o[2] = (__bf16)f0.z; o[3] = (__bf16)f0.w;
        o[4] = (__bf16)f1.x; o[5] = (__bf16)f1.y; o[6] = (__bf16)f1.z; o[7] = (__bf16)f1.w;
        const size_t unit = ((size_t)((b * 32 + kt) * 64 + row)) * 16 + (u ^ (row & 7));
        *(bfv8*)&kb[unit * 8] = o;
    } else {                       // V part: 8*32*128*8 units
        const int m  = t - 262144;
        const int b  = m >> 15;
        const int kt = (m >> 10) & 31;
        const int u  = (m >> 7) & 7;
        const int d  = m & 127;
        bfv8 o;
#pragma unroll
        for (int j = 0; j < 8; ++j) {
            const int kv = kt * 64 + u * 8 + j;
            o[j] = (__bf16)v[((size_t)(b * S + kv)) * D + d];
        }
        const size_t unit = ((size_t)((b * 32 + kt) * 128 + d)) * 8 + (u ^ (d & 7));
        *(bfv8*)&vtb[unit * 8] = o;
    }
}

// ============ main kernel ============
__global__ __launch_bounds__(256) void attn_main(
    const float* __restrict__ q, const float* __restrict__ rep,
    const __bf16* __restrict__ kb, const __bf16* __restrict__ vtb,
    float* __restrict__ out, float* __restrict__ attn)
{
    __shared__ __attribute__((aligned(16))) __bf16 qs[BQ][136];
    __shared__ __attribute__((aligned(16))) __bf16 kbuf[2][8192];   // 16KB x2
    __shared__ __attribute__((aligned(16))) __bf16 vbuf[2][8192];   // 16KB x2
    __shared__ __attribute__((aligned(16))) __bf16 ps[BQ][72];
    __shared__ float redsum[2][2][16];
    __shared__ float dinv_lds[BQ];

    const int tid  = threadIdx.x;
    const int bid  = blockIdx.x;
    const int b    = bid & 7;
    const int qt   = (NQT - 1) - (bid >> 3);
    const int i0   = qt * BQ;
    const int NT   = ((qt * BQ + (BQ - 2)) >> 6) + 1;

    const int lane = tid & 63;
    const int w    = tid >> 6;
    const int rg   = w >> 1;
    const int ch   = w & 1;
    const int lr   = lane & 15;
    const int lg   = lane >> 4;

    // async tile stagers: 4 x 1KB issues per wave per 16KB tile
    auto stageK = [&](int buf, int kt) {
        const char* src = (const char*)kb + (((size_t)(b * 32 + kt)) << 14);
        char* dst = (char*)&kbuf[buf][0];
#pragma unroll
        for (int i2 = 0; i2 < 4; ++i2) {
            const int n0 = (w * 4 + i2) * 64;
            gload_lds16(src + (size_t)(n0 + lane) * 16, dst + (size_t)n0 * 16);
        }
    };
    auto stageV = [&](int buf, int kt) {
        const char* src = (const char*)vtb + (((size_t)(b * 32 + kt)) << 14);
        char* dst = (char*)&vbuf[buf][0];
#pragma unroll
        for (int i2 = 0; i2 < 4; ++i2) {
            const int n0 = (w * 4 + i2) * 64;
            gload_lds16(src + (size_t)(n0 + lane) * 16, dst + (size_t)n0 * 16);
        }
    };
    // swizzled frag readers
    auto kfrag = [&](int buf, int row, int u) -> bfv8 {
        return *(const bfv8*)&kbuf[buf][(row * 16 + (u ^ (row & 7))) * 8];
    };
    auto vfrag = [&](int buf, int drow, int u) -> bfv8 {
        return *(const bfv8*)&vbuf[buf][(drow * 8 + (u ^ (drow & 7))) * 8];
    };

    // ---- stage Q tile -> bf16 LDS (fp32 inline) + issue K tile 0 ----
    for (int c = tid; c < BQ * 16; c += 256) {
        const int row = c >> 4, c8 = c & 15;
        const float4 f0 = *(const float4*)&q[((size_t)(b * S + i0 + row)) * D + c8 * 8];
        const float4 f1 = *(const float4*)&q[((size_t)(b * S + i0 + row)) * D + c8 * 8 + 4];
        bfv8 t;
        t[0] = (__bf16)f0.x; t[1] = (__bf16)f0.y; t[2] = (__bf16)f0.z; t[3] = (__bf16)f0.w;
        t[4] = (__bf16)f1.x; t[5] = (__bf16)f1.y; t[6] = (__bf16)f1.z; t[7] = (__bf16)f1.w;
        *(bfv8*)&qs[row][c8 * 8] = t;
    }
    stageK(0, 0);
    __syncthreads();

    bfv8 qa[4];
#pragma unroll
    for (int ks = 0; ks < 4; ++ks)
        qa[ks] = *(const bfv8*)&qs[rg * 16 + lr][ks * 32 + lg * 8];

    int  i_r[4];
    bool bi[4];
#pragma unroll
    for (int r = 0; r < 4; ++r) {
        i_r[r] = i0 + rg * 16 + lg * 4 + r;
        bi[r]  = rep[(size_t)b * S + i_r[r]] > 0.5f;
    }

    // ================= pass A: masked row sums =================
    float lsum[4] = {0.f, 0.f, 0.f, 0.f};
    int cur = 0;
    for (int kt = 0; kt < NT; ++kt) {
        if (kt + 1 < NT) stageK(cur ^ 1, kt + 1);

        f32x4 acc0 = {0.f, 0.f, 0.f, 0.f}, acc1 = {0.f, 0.f, 0.f, 0.f};
#pragma unroll
        for (int ks = 0; ks < 4; ++ks) {
            const bfv8 b0 = kfrag(cur, ch * 32 + lr, ks * 4 + lg);
            const bfv8 b1 = kfrag(cur, ch * 32 + 16 + lr, ks * 4 + lg);
            acc0 = mfma16(qa[ks], b0, acc0);
            acc1 = mfma16(qa[ks], b1, acc1);
        }

        const int j0 = kt * BK + ch * 32 + lr;
        const int j1 = j0 + 16;
        const bool vj0 = rep[(size_t)b * S + j0] > 0.5f;
        const bool vj1 = rep[(size_t)b * S + j1] > 0.5f;
#pragma unroll
        for (int r = 0; r < 4; ++r) {
            const int i = i_r[r];
            const float p0 = (bi[r] && vj0 && (j0 < i))
                ? __expf(acc0[r] * INV_SQRT_D - (float)(i - j0)) : 0.f;
            const float p1 = (bi[r] && vj1 && (j1 < i))
                ? __expf(acc1[r] * INV_SQRT_D - (float)(i - j1)) : 0.f;
            lsum[r] += p0 + p1;
        }
        __syncthreads();   // drains prefetch vmcnt + retires kbuf[cur] reads
        cur ^= 1;
    }

    // issue pass-B tile 0 now; reduction barriers below drain it
    stageK(0, 0);
    stageV(0, 0);

    // ---- reduce row sums ----
#pragma unroll
    for (int r = 0; r < 4; ++r) {
        lsum[r] += __shfl_xor(lsum[r], 1);
        lsum[r] += __shfl_xor(lsum[r], 2);
        lsum[r] += __shfl_xor(lsum[r], 4);
        lsum[r] += __shfl_xor(lsum[r], 8);
    }
    if (lr == 0) {
#pragma unroll
        for (int r = 0; r < 4; ++r) redsum[rg][ch][lg * 4 + r] = lsum[r];
    }
    __syncthreads();
    if (tid < BQ) {
        const float s = redsum[tid >> 4][0][tid & 15] + redsum[tid >> 4][1][tid & 15];
        dinv_lds[tid] = 1.f / (s + ((s == 0.f) ? 1.f : 0.f) + 1e-20f);
    }
    __syncthreads();

    float dinv[4];
#pragma unroll
    for (int r = 0; r < 4; ++r) dinv[r] = dinv_lds[rg * 16 + lg * 4 + r];

    // ================= pass B: recompute, attn, PV =================
    f32x4 oacc[4];
#pragma unroll
    for (int nf = 0; nf < 4; ++nf) oacc[nf] = (f32x4){0.f, 0.f, 0.f, 0.f};

    cur = 0;
    for (int kt = 0; kt < NT; ++kt) {
        if (kt + 1 < NT) { stageK(cur ^ 1, kt + 1); stageV(cur ^ 1, kt + 1); }

        f32x4 acc0 = {0.f, 0.f, 0.f, 0.f}, acc1 = {0.f, 0.f, 0.f, 0.f};
#pragma unroll
        for (int ks = 0; ks < 4; ++ks) {
            const bfv8 b0 = kfrag(cur, ch * 32 + lr, ks * 4 + lg);
            const bfv8 b1 = kfrag(cur, ch * 32 + 16 + lr, ks * 4 + lg);
            acc0 = mfma16(qa[ks], b0, acc0);
            acc1 = mfma16(qa[ks], b1, acc1);
        }

        const int j0 = kt * BK + ch * 32 + lr;
        const int j1 = j0 + 16;
        const bool vj0 = rep[(size_t)b * S + j0] > 0.5f;
        const bool vj1 = rep[(size_t)b * S + j1] > 0.5f;
#pragma unroll
        for (int r = 0; r < 4; ++r) {
            const int i = i_r[r];
            const float p0 = (bi[r] && vj0 && (j0 < i))
                ? __expf(acc0[r] * INV_SQRT_D - (float)(i - j0)) * dinv[r] : 0.f;
            const float p1 = (bi[r] && vj1 && (j1 < i))
                ? __expf(acc1[r] * INV_SQRT_D - (float)(i - j1)) * dinv[r] : 0.f;
            ps[rg * 16 + lg * 4 + r][ch * 32 + lr]      = (__bf16)p0;
            ps[rg * 16 + lg * 4 + r][ch * 32 + 16 + lr] = (__bf16)p1;
        }

        // mid barrier: publish ps WITHOUT draining prefetch vmcnt
        asm volatile("s_waitcnt lgkmcnt(0)" ::: "memory");
        __builtin_amdgcn_s_barrier();
        asm volatile("" ::: "memory");

        // coalesced attn tile store from ps
        {
            const int arow = tid >> 3, ac = (tid & 7) * 8;
            const bfv8 t = *(const bfv8*)&ps[arow][ac];
            float4 f0, f1;
            f0.x = (float)t[0]; f0.y = (float)t[1]; f0.z = (float)t[2]; f0.w = (float)t[3];
            f1.x = (float)t[4]; f1.y = (float)t[5]; f1.z = (float)t[6]; f1.w = (float)t[7];
            float* ap = &attn[((size_t)(b * S + i0 + arow)) * S + kt * BK + ac];
            *(float4*)ap = f0;
            *(float4*)(ap + 4) = f1;
        }

        // PV from vbuf[cur]
#pragma unroll
        for (int ks = 0; ks < 2; ++ks) {
            const bfv8 pa = *(const bfv8*)&ps[rg * 16 + lr][ks * 32 + lg * 8];
#pragma unroll
            for (int nf = 0; nf < 4; ++nf) {
                const bfv8 vf = vfrag(cur, ch * 64 + nf * 16 + lr, ks * 4 + lg);
                oacc[nf] = mfma16(pa, vf, oacc[nf]);
            }
        }
        __syncthreads();   // drains prefetch + retires kbuf/vbuf/ps reads
        cur ^= 1;
    }

    // ---- write out ----
#pragma unroll
    for (int nf = 0; nf < 4; ++nf)
#pragma unroll
        for (int r = 0; r < 4; ++r)
            out[((size_t)(b * S + i_r[r])) * D + ch * 64 + nf * 16 + lr] = oacc[nf][r];

    // ---- zero-fill attn tiles above the block diagonal ----
    const int zt = NKT - NT;
    const float4 z4 = make_float4(0.f, 0.f, 0.f, 0.f);
    for (int u = tid; u < zt * 512; u += 256) {
        const int t   = u >> 9;
        const int rem = u & 511;
        const int row = rem >> 4;
        const int c4  = rem & 15;
        *(float4*)&attn[((size_t)(b * S + i0 + row)) * S + (NT + t) * BK + c4 * 4] = z4;
    }
}

// ============ fallback (round-2 proven kernel) if ws too small ============
__global__ __launch_bounds__(256) void attn_kernel_fb(
    const float* __restrict__ q, const float* __restrict__ k,
    const float* __restrict__ v, const float* __restrict__ rep,
    float* __restrict__ out, float* __restrict__ attn)
{
    __shared__ __attribute__((aligned(16))) __bf16 qs [BQ][136];
    __shared__ __attribute__((aligned(16))) __bf16 ksm[BK][136];
    __shared__ __attribute__((aligned(16))) __bf16 vsT[D][72];
    __shared__ __attribute__((aligned(16))) __bf16 ps [BQ][72];
    __shared__ float redsum[2][2][16];
    __shared__ float dinv_lds[BQ];

    const int tid  = threadIdx.x;
    const int bid  = blockIdx.x;
    const int b    = bid & 7;
    const int qt   = (NQT - 1) - (bid >> 3);
    const int i0   = qt * BQ;
    const int NT   = ((qt * BQ + (BQ - 2)) >> 6) + 1;

    const int lane = tid & 63;
    const int w    = tid >> 6;
    const int rg   = w >> 1;
    const int ch   = w & 1;
    const int lr   = lane & 15;
    const int lg   = lane >> 4;

    for (int c = tid; c < BQ * 16; c += 256) {
        const int row = c >> 4, c8 = c & 15;
        const float4 f0 = *(const float4*)&q[((size_t)(b * S + i0 + row)) * D + c8 * 8];
        const float4 f1 = *(const float4*)&q[((size_t)(b * S + i0 + row)) * D + c8 * 8 + 4];
        bfv8 t;
        t[0] = (__bf16)f0.x; t[1] = (__bf16)f0.y; t[2] = (__bf16)f0.z; t[3] = (__bf16)f0.w;
        t[4] = (__bf16)f1.x; t[5] = (__bf16)f1.y; t[6] = (__bf16)f1.z; t[7] = (__bf16)f1.w;
        *(bfv8*)&qs[row][c8 * 8] = t;
    }
    __syncthreads();

    bfv8 qa[4];
#pragma unroll
    for (int ks = 0; ks < 4; ++ks)
        qa[ks] = *(const bfv8*)&qs[rg * 16 + lr][ks * 32 + lg * 8];

    int  i_r[4];
    bool bi[4];
#pragma unroll
    for (int r = 0; r < 4; ++r) {
        i_r[r] = i0 + rg * 16 + lg * 4 + r;
        bi[r]  = rep[(size_t)b * S + i_r[r]] > 0.5f;
    }

    float lsum[4] = {0.f, 0.f, 0.f, 0.f};
    for (int kt = 0; kt < NT; ++kt) {
        __syncthreads();
        for (int c = tid; c < BK * 16; c += 256) {
            const int row = c >> 4, c8 = c & 15;
            const float4 f0 = *(const float4*)&k[((size_t)(b * S + kt * BK + row)) * D + c8 * 8];
            const float4 f1 = *(const float4*)&k[((size_t)(b * S + kt * BK + row)) * D + c8 * 8 + 4];
            bfv8 t;
        t[0] = (__bf16)f0.x; t[1] = (__bf16)f0.y; t[2] = (__bf16)f0.z; t[3] = (__bf16)f0.w;
        t[4] = (__bf16)f1.x; t[5] = (__bf16)f1.y; t[6] = (__bf16)f1.z; t[7] = (__bf16)f1.w;
            *(bfv8*)&ksm[row][c8 * 8] = t;
        }
        __syncthreads();

        f32x4 acc0 = {0.f, 0.f, 0.f, 0.f}, acc1 = {0.f, 0.f, 0.f, 0.f};
#pragma unroll
        for (int ks = 0; ks < 4; ++ks) {
            const bfv8 b0 = *(const bfv8*)&ksm[ch * 32 + lr][ks * 32 + lg * 8];
            const bfv8 b1 = *(const bfv8*)&ksm[ch * 32 + 16 + lr][ks * 32 + lg * 8];
            acc0 = mfma16(qa[ks], b0, acc0);
            acc1 = mfma16(qa[ks], b1, acc1);
        }
        const int j0 = kt * BK + ch * 32 + lr;
        const int j1 = j0 + 16;
        const bool vj0 = rep[(size_t)b * S + j0] > 0.5f;
        const bool vj1 = rep[(size_t)b * S + j1] > 0.5f;
#pragma unroll
        for (int r = 0; r < 4; ++r) {
            const int i = i_r[r];
            const float p0 = (bi[r] && vj0 && (j0 < i))
                ? __expf(acc0[r] * INV_SQRT_D - (float)(i - j0)) : 0.f;
            const float p1 = (bi[r] && vj1 && (j1 < i))
                ? __expf(acc1[r] * INV_SQRT_D - (float)(i - j1)) : 0.f;
            lsum[r] += p0 + p1;
        }
    }

#pragma unroll
    for (int r = 0; r < 4; ++r) {
        lsum[r] += __shfl_xor(lsum[r], 1);
        lsum[r] += __shfl_xor(lsum[r], 2);
        lsum[r] += __shfl_xor(lsum[r], 4);
        lsum[r] += __shfl_xor(lsum[r], 8);
    }
    if (lr == 0) {
#pragma unroll
        for (int r = 0; r < 4; ++r) redsum[rg][ch][lg * 4 + r] = lsum[r];
    }
    __syncthreads();
    if (tid < BQ) {
        const float s = redsum[tid >> 4][0][tid & 15] + redsum[tid >> 4][1][tid & 15];
        dinv_lds[tid] = 1.f / (s + ((s == 0.f) ? 1.f : 0.f) + 1e-20f);
    }
    __syncthreads();

    float dinv[4];
#pragma unroll
    for (int r = 0; r < 4; ++r) dinv[r] = dinv_lds[rg * 16 + lg * 4 + r];

    f32x4 oacc[4];
#pragma unroll
    for (int nf = 0; nf < 4; ++nf) oacc[nf] = (f32x4){0.f, 0.f, 0.f, 0.f};

    for (int kt = 0; kt < NT; ++kt) {
        __syncthreads();
        for (int c = tid; c < BK * 16; c += 256) {
            const int row = c >> 4, c8 = c & 15;
            const float4 f0 = *(const float4*)&k[((size_t)(b * S + kt * BK + row)) * D + c8 * 8];
            const float4 f1 = *(const float4*)&k[((size_t)(b * S + kt * BK + row)) * D + c8 * 8 + 4];
            bfv8 t;
        t[0] = (__bf16)f0.x; t[1] = (__bf16)f0.y; t[2] = (__bf16)f0.z; t[3] = (__bf16)f0.w;
        t[4] = (__bf16)f1.x; t[5] = (__bf16)f1.y; t[6] = (__bf16)f1.z; t[7] = (__bf16)f1.w;
            *(bfv8*)&ksm[row][c8 * 8] = t;
        }
        for (int u = tid; u < 1024; u += 256) {
            const int p  = u & 31;
            const int dq = u >> 5;
            const float4 va = *(const float4*)&v[((size_t)(b * S + kt * BK + 2 * p)) * D + dq * 4];
            const float4 vb = *(const float4*)&v[((size_t)(b * S + kt * BK + 2 * p + 1)) * D + dq * 4];
            *(unsigned int*)&vsT[dq * 4 + 0][2 * p] = pack2(va.x, vb.x);
            *(unsigned int*)&vsT[dq * 4 + 1][2 * p] = pack2(va.y, vb.y);
            *(unsigned int*)&vsT[dq * 4 + 2][2 * p] = pack2(va.z, vb.z);
            *(unsigned int*)&vsT[dq * 4 + 3][2 * p] = pack2(va.w, vb.w);
        }
        __syncthreads();

        f32x4 acc0 = {0.f, 0.f, 0.f, 0.f}, acc1 = {0.f, 0.f, 0.f, 0.f};
#pragma unroll
        for (int ks = 0; ks < 4; ++ks) {
            const bfv8 b0 = *(const bfv8*)&ksm[ch * 32 + lr][ks * 32 + lg * 8];
            const bfv8 b1 = *(const bfv8*)&ksm[ch * 32 + 16 + lr][ks * 32 + lg * 8];
            acc0 = mfma16(qa[ks], b0, acc0);
            acc1 = mfma16(qa[ks], b1, acc1);
        }
        const int j0 = kt * BK + ch * 32 + lr;
        const int j1 = j0 + 16;
        const bool vj0 = rep[(size_t)b * S + j0] > 0.5f;
        const bool vj1 = rep[(size_t)b * S + j1] > 0.5f;
#pragma unroll
        for (int r = 0; r < 4; ++r) {
            const int i = i_r[r];
            const float p0 = (bi[r] && vj0 && (j0 < i))
                ? __expf(acc0[r] * INV_SQRT_D - (float)(i - j0)) * dinv[r] : 0.f;
            const float p1 = (bi[r] && vj1 && (j1 < i))
                ? __expf(acc1[r] * INV_SQRT_D - (float)(i - j1)) * dinv[r] : 0.f;
            attn[((size_t)(b * S + i)) * S + j0] = p0;
            attn[((size_t)(b * S + i)) * S + j1] = p1;
            ps[rg * 16 + lg * 4 + r][ch * 32 + lr]      = (__bf16)p0;
            ps[rg * 16 + lg * 4 + r][ch * 32 + 16 + lr] = (__bf16)p1;
        }
        __syncthreads();

#pragma unroll
        for (int ks = 0; ks < 2; ++ks) {
            const bfv8 pa = *(const bfv8*)&ps[rg * 16 + lr][ks * 32 + lg * 8];
#pragma unroll
            for (int nf = 0; nf < 4; ++nf) {
                const bfv8 vf = *(const bfv8*)&vsT[ch * 64 + nf * 16 + lr][ks * 32 + lg * 8];
                oacc[nf] = mfma16(pa, vf, oacc[nf]);
            }
        }
    }

#pragma unroll
    for (int nf = 0; nf < 4; ++nf)
#pragma unroll
        for (int r = 0; r < 4; ++r)
            out[((size_t)(b * S + i_r[r])) * D + ch * 64 + nf * 16 + lr] = oacc[nf][r];

    const int zt = NKT - NT;
    const float4 z4 = make_float4(0.f, 0.f, 0.f, 0.f);
    for (int u = tid; u < zt * 512; u += 256) {
        const int t   = u >> 9;
        const int rem = u & 511;
        const int row = rem >> 4;
        const int c4  = rem & 15;
        *(float4*)&attn[((size_t)(b * S + i0 + row)) * S + (NT + t) * BK + c4 * 4] = z4;
    }
}

extern "C" void kernel_launch(void* const* d_in, const int* in_sizes, int n_in,
                              void* d_out, int out_size, void* d_ws, size_t ws_size,
                              hipStream_t stream)
{
    const float* q   = (const float*)d_in[0];
    const float* k   = (const float*)d_in[1];
    const float* v   = (const float*)d_in[2];
    const float* rep = (const float*)d_in[3];
    float* out  = (float*)d_out;
    float* attn = out + (size_t)NBATCH * S * D;

    const size_t kb_elems = (size_t)NBATCH * S * D;       // 2,097,152 bf16 = 4MB
    const size_t need = kb_elems * 2 * 2;                 // kb + vtb, bytes

    if (ws_size < need) {
        hipLaunchKernelGGL(attn_kernel_fb, dim3(NBATCH * NQT), dim3(256), 0, stream,
                           q, k, v, rep, out, attn);
        return;
    }

    __bf16* kb  = (__bf16*)d_ws;
    __bf16* vtb = kb + kb_elems;

    hipLaunchKernelGGL(prep_kernel, dim3(2048), dim3(256), 0, stream, k, v, kb, vtb);
    hipLaunchKernelGGL(attn_main, dim3(NBATCH * NQT), dim3(256), 0, stream,
                       q, rep, kb, vtb, out, attn);
}

// Round 5
// 72.584 us; speedup vs baseline: 8.3781x; 1.0853x over previous
//
#include <hip/hip_runtime.h>

#define NBATCH 8
#define S 2048
#define D 128
#define BQ 32
#define BK 64
#define NKT 32
#define NQT 64
#define INV_SQRT_D 0.08838834764831845f

typedef __bf16 bfv8 __attribute__((ext_vector_type(8)));
typedef float f32x4 __attribute__((ext_vector_type(4)));

__device__ __forceinline__ f32x4 mfma16(bfv8 a, bfv8 b, f32x4 c) {
    return __builtin_amdgcn_mfma_f32_16x16x32_bf16(a, b, c, 0, 0, 0);
}

__device__ __forceinline__ unsigned int pack2(float lo, float hi) {
    unsigned short a = __builtin_bit_cast(unsigned short, (__bf16)lo);
    unsigned short b = __builtin_bit_cast(unsigned short, (__bf16)hi);
    return (unsigned int)a | ((unsigned int)b << 16);
}

__device__ __forceinline__ void gload_lds16(const void* g, void* l) {
    __builtin_amdgcn_global_load_lds(
        (const __attribute__((address_space(1))) unsigned int*)g,
        (__attribute__((address_space(3))) unsigned int*)l, 16, 0, 0);
}

// ============ prep: K -> bf16 swizzled tiles; V -> bf16 transposed swizzled ============
__global__ __launch_bounds__(256) void prep_kernel(
    const float* __restrict__ k, const float* __restrict__ v,
    __bf16* __restrict__ kb, __bf16* __restrict__ vtb)
{
    const int t = blockIdx.x * 256 + threadIdx.x;
    if (t < 262144) {              // K part
        const int b   = t >> 15;
        const int kt  = (t >> 10) & 31;
        const int row = (t >> 4) & 63;
        const int u   = t & 15;
        const float4 f0 = *(const float4*)&k[((size_t)(b * S + kt * 64 + row)) * D + u * 8];
        const float4 f1 = *(const float4*)&k[((size_t)(b * S + kt * 64 + row)) * D + u * 8 + 4];
        bfv8 o;
        o[0] = (__bf16)f0.x; o[1] = (__bf16)f0.y; o[2] = (__bf16)f0.z; o[3] = (__bf16)f0.w;
        o[4] = (__bf16)f1.x; o[5] = (__bf16)f1.y; o[6] = (__bf16)f1.z; o[7] = (__bf16)f1.w;
        const size_t unit = ((size_t)((b * 32 + kt) * 64 + row)) * 16 + (u ^ (row & 7));
        *(bfv8*)&kb[unit * 8] = o;
    } else {                       // V part (transpose)
        const int m  = t - 262144;
        const int b  = m >> 15;
        const int kt = (m >> 10) & 31;
        const int u  = (m >> 7) & 7;
        const int d  = m & 127;
        bfv8 o;
#pragma unroll
        for (int j = 0; j < 8; ++j) {
            const int kv = kt * 64 + u * 8 + j;
            o[j] = (__bf16)v[((size_t)(b * S + kv)) * D + d];
        }
        const size_t unit = ((size_t)((b * 32 + kt) * 128 + d)) * 8 + (u ^ (d & 7));
        *(bfv8*)&vtb[unit * 8] = o;
    }
}

// ============ main kernel ============
__global__ __launch_bounds__(256) void attn_main(
    const float* __restrict__ q, const float* __restrict__ rep,
    const __bf16* __restrict__ kb, const __bf16* __restrict__ vtb,
    float* __restrict__ out, float* __restrict__ attn)
{
    // 4 x 16KB tile slots: pass A -> K rotation slots 0..2; pass B -> K:0/1, V:2/3
    __shared__ __attribute__((aligned(16))) __bf16 slots[4][8192];
    __shared__ __attribute__((aligned(16))) __bf16 qs[BQ][136];
    __shared__ __attribute__((aligned(16))) __bf16 ps[BQ][72];
    __shared__ float redsum[2][2][16];
    __shared__ float dinv_lds[BQ];

    const int tid  = threadIdx.x;
    const int bid  = blockIdx.x;
    const int b    = bid & 7;
    const int qt   = (NQT - 1) - (bid >> 3);
    const int i0   = qt * BQ;
    const int NT   = ((qt * BQ + (BQ - 2)) >> 6) + 1;

    const int lane = tid & 63;
    const int w    = tid >> 6;
    const int rg   = w >> 1;
    const int ch   = w & 1;
    const int lr   = lane & 15;
    const int lg   = lane >> 4;

    auto stageK = [&](int kt, int slot) {
        const char* src = (const char*)kb + (((size_t)(b * 32 + kt)) << 14);
        char* dst = (char*)&slots[slot][0];
#pragma unroll
        for (int i2 = 0; i2 < 4; ++i2) {
            const int n0 = (w * 4 + i2) * 64;
            gload_lds16(src + (size_t)(n0 + lane) * 16, dst + (size_t)n0 * 16);
        }
    };
    auto stageV = [&](int kt, int slot) {
        const char* src = (const char*)vtb + (((size_t)(b * 32 + kt)) << 14);
        char* dst = (char*)&slots[slot][0];
#pragma unroll
        for (int i2 = 0; i2 < 4; ++i2) {
            const int n0 = (w * 4 + i2) * 64;
            gload_lds16(src + (size_t)(n0 + lane) * 16, dst + (size_t)n0 * 16);
        }
    };
    auto kfrag = [&](int slot, int row, int u) -> bfv8 {
        return *(const bfv8*)&slots[slot][(row * 16 + (u ^ (row & 7))) * 8];
    };
    auto vfrag = [&](int slot, int drow, int u) -> bfv8 {
        return *(const bfv8*)&slots[slot][(drow * 8 + (u ^ (drow & 7))) * 8];
    };

    // prologue prefetch: K tiles 0,1 into slots 0,1
    stageK(0, 0);
    if (NT > 1) stageK(1, 1);

    // ---- stage Q tile -> bf16 LDS ----
    for (int c = tid; c < BQ * 16; c += 256) {
        const int row = c >> 4, c8 = c & 15;
        const float4 f0 = *(const float4*)&q[((size_t)(b * S + i0 + row)) * D + c8 * 8];
        const float4 f1 = *(const float4*)&q[((size_t)(b * S + i0 + row)) * D + c8 * 8 + 4];
        bfv8 t;
        t[0] = (__bf16)f0.x; t[1] = (__bf16)f0.y; t[2] = (__bf16)f0.z; t[3] = (__bf16)f0.w;
        t[4] = (__bf16)f1.x; t[5] = (__bf16)f1.y; t[6] = (__bf16)f1.z; t[7] = (__bf16)f1.w;
        *(bfv8*)&qs[row][c8 * 8] = t;
    }

    // ---- per-lane column-validity bitmasks (hoists ALL per-iter rep loads) ----
    unsigned int vm0 = 0, vm1 = 0;
    for (int kt = 0; kt < NT; ++kt) {
        const unsigned int t0 = (rep[(size_t)b * S + kt * BK + ch * 32 + lr]      > 0.5f) ? 1u : 0u;
        const unsigned int t1 = (rep[(size_t)b * S + kt * BK + ch * 32 + 16 + lr] > 0.5f) ? 1u : 0u;
        vm0 |= t0 << kt;
        vm1 |= t1 << kt;
    }

    int  i_r[4];
    bool bi[4];
#pragma unroll
    for (int r = 0; r < 4; ++r) {
        i_r[r] = i0 + rg * 16 + lg * 4 + r;
        bi[r]  = rep[(size_t)b * S + i_r[r]] > 0.5f;
    }
    __syncthreads();   // qs ready (also drains prologue prefetch; one-time)

    bfv8 qa[4];
#pragma unroll
    for (int ks = 0; ks < 4; ++ks)
        qa[ks] = *(const bfv8*)&qs[rg * 16 + lr][ks * 32 + lg * 8];

    // ================= pass A: masked row sums (3-slot K rotation, depth-2) =================
    float lsum[4] = {0.f, 0.f, 0.f, 0.f};
    for (int kt = 0; kt < NT; ++kt) {
        if (kt + 1 < NT) { asm volatile("s_waitcnt vmcnt(4)" ::: "memory"); }
        else             { asm volatile("s_waitcnt vmcnt(0)" ::: "memory"); }
        __builtin_amdgcn_s_barrier();
        asm volatile("" ::: "memory");

        const int slot = kt % 3;
        f32x4 acc0 = {0.f, 0.f, 0.f, 0.f}, acc1 = {0.f, 0.f, 0.f, 0.f};
#pragma unroll
        for (int ks = 0; ks < 4; ++ks) {
            const bfv8 b0 = kfrag(slot, ch * 32 + lr, ks * 4 + lg);
            const bfv8 b1 = kfrag(slot, ch * 32 + 16 + lr, ks * 4 + lg);
            acc0 = mfma16(qa[ks], b0, acc0);
            acc1 = mfma16(qa[ks], b1, acc1);
        }

        const int j0 = kt * BK + ch * 32 + lr;
        const int j1 = j0 + 16;
        const bool vj0 = (vm0 >> kt) & 1;
        const bool vj1 = (vm1 >> kt) & 1;
#pragma unroll
        for (int r = 0; r < 4; ++r) {
            const int i = i_r[r];
            const float p0 = (bi[r] && vj0 && (j0 < i))
                ? __expf(acc0[r] * INV_SQRT_D - (float)(i - j0)) : 0.f;
            const float p1 = (bi[r] && vj1 && (j1 < i))
                ? __expf(acc1[r] * INV_SQRT_D - (float)(i - j1)) : 0.f;
            lsum[r] += p0 + p1;
        }

        if (kt + 2 < NT) stageK(kt + 2, (kt + 2) % 3);
    }

    // issue pass-B tile 0 prefetch; reduction barriers below drain it
    stageK(0, 0);
    stageV(0, 2);

    // ---- reduce row sums ----
#pragma unroll
    for (int r = 0; r < 4; ++r) {
        lsum[r] += __shfl_xor(lsum[r], 1);
        lsum[r] += __shfl_xor(lsum[r], 2);
        lsum[r] += __shfl_xor(lsum[r], 4);
        lsum[r] += __shfl_xor(lsum[r], 8);
    }
    if (lr == 0) {
#pragma unroll
        for (int r = 0; r < 4; ++r) redsum[rg][ch][lg * 4 + r] = lsum[r];
    }
    __syncthreads();
    if (tid < BQ) {
        const float s = redsum[tid >> 4][0][tid & 15] + redsum[tid >> 4][1][tid & 15];
        dinv_lds[tid] = 1.f / (s + ((s == 0.f) ? 1.f : 0.f) + 1e-20f);
    }
    __syncthreads();

    float dinv[4];
#pragma unroll
    for (int r = 0; r < 4; ++r) dinv[r] = dinv_lds[rg * 16 + lg * 4 + r];

    // ================= pass B: recompute, attn, PV (stores never drained in-loop) ==========
    f32x4 oacc[4];
#pragma unroll
    for (int nf = 0; nf < 4; ++nf) oacc[nf] = (f32x4){0.f, 0.f, 0.f, 0.f};

    for (int kt = 0; kt < NT; ++kt) {
        const int kslot = kt & 1;
        const int vslot = 2 + (kt & 1);

        // issue next-tile stage loads FIRST (oldest in vmcnt queue)
        if (kt + 1 < NT) { stageK(kt + 1, (kt + 1) & 1); stageV(kt + 1, 2 + ((kt + 1) & 1)); }

        f32x4 acc0 = {0.f, 0.f, 0.f, 0.f}, acc1 = {0.f, 0.f, 0.f, 0.f};
#pragma unroll
        for (int ks = 0; ks < 4; ++ks) {
            const bfv8 b0 = kfrag(kslot, ch * 32 + lr, ks * 4 + lg);
            const bfv8 b1 = kfrag(kslot, ch * 32 + 16 + lr, ks * 4 + lg);
            acc0 = mfma16(qa[ks], b0, acc0);
            acc1 = mfma16(qa[ks], b1, acc1);
        }

        const int j0 = kt * BK + ch * 32 + lr;
        const int j1 = j0 + 16;
        const bool vj0 = (vm0 >> kt) & 1;
        const bool vj1 = (vm1 >> kt) & 1;
#pragma unroll
        for (int r = 0; r < 4; ++r) {
            const int i = i_r[r];
            const float p0 = (bi[r] && vj0 && (j0 < i))
                ? __expf(acc0[r] * INV_SQRT_D - (float)(i - j0)) * dinv[r] : 0.f;
            const float p1 = (bi[r] && vj1 && (j1 < i))
                ? __expf(acc1[r] * INV_SQRT_D - (float)(i - j1)) * dinv[r] : 0.f;
            ps[rg * 16 + lg * 4 + r][ch * 32 + lr]      = (__bf16)p0;
            ps[rg * 16 + lg * 4 + r][ch * 32 + 16 + lr] = (__bf16)p1;
        }

        // mid barrier: publish ps, keep vmcnt in flight
        asm volatile("s_waitcnt lgkmcnt(0)" ::: "memory");
        __builtin_amdgcn_s_barrier();
        asm volatile("" ::: "memory");

        // coalesced attn tile store from ps (2 stores, newest in queue)
        {
            const int arow = tid >> 3, ac = (tid & 7) * 8;
            const bfv8 t = *(const bfv8*)&ps[arow][ac];
            float4 f0, f1;
            f0.x = (float)t[0]; f0.y = (float)t[1]; f0.z = (float)t[2]; f0.w = (float)t[3];
            f1.x = (float)t[4]; f1.y = (float)t[5]; f1.z = (float)t[6]; f1.w = (float)t[7];
            float* ap = &attn[((size_t)(b * S + i0 + arow)) * S + kt * BK + ac];
            *(float4*)ap = f0;
            *(float4*)(ap + 4) = f1;
        }

        // PV
#pragma unroll
        for (int ks = 0; ks < 2; ++ks) {
            const bfv8 pa = *(const bfv8*)&ps[rg * 16 + lr][ks * 32 + lg * 8];
#pragma unroll
            for (int nf = 0; nf < 4; ++nf) {
                const bfv8 vf = vfrag(vslot, ch * 64 + nf * 16 + lr, ks * 4 + lg);
                oacc[nf] = mfma16(pa, vf, oacc[nf]);
            }
        }

        // end barrier: retire next-tile loads (8), leave attn stores (2) in flight
        asm volatile("s_waitcnt vmcnt(2)" ::: "memory");
        __builtin_amdgcn_s_barrier();
        asm volatile("" ::: "memory");
    }

    // ---- write out ----
#pragma unroll
    for (int nf = 0; nf < 4; ++nf)
#pragma unroll
        for (int r = 0; r < 4; ++r)
            out[((size_t)(b * S + i_r[r])) * D + ch * 64 + nf * 16 + lr] = oacc[nf][r];

    // ---- zero-fill attn tiles above the block diagonal ----
    const int zt = NKT - NT;
    const float4 z4 = make_float4(0.f, 0.f, 0.f, 0.f);
    for (int u = tid; u < zt * 512; u += 256) {
        const int t   = u >> 9;
        const int rem = u & 511;
        const int row = rem >> 4;
        const int c4  = rem & 15;
        *(float4*)&attn[((size_t)(b * S + i0 + row)) * S + (NT + t) * BK + c4 * 4] = z4;
    }
}

// ============ fallback (proven) if ws too small ============
__global__ __launch_bounds__(256) void attn_kernel_fb(
    const float* __restrict__ q, const float* __restrict__ k,
    const float* __restrict__ v, const float* __restrict__ rep,
    float* __restrict__ out, float* __restrict__ attn)
{
    __shared__ __attribute__((aligned(16))) __bf16 qs [BQ][136];
    __shared__ __attribute__((aligned(16))) __bf16 ksm[BK][136];
    __shared__ __attribute__((aligned(16))) __bf16 vsT[D][72];
    __shared__ __attribute__((aligned(16))) __bf16 ps [BQ][72];
    __shared__ float redsum[2][2][16];
    __shared__ float dinv_lds[BQ];

    const int tid  = threadIdx.x;
    const int bid  = blockIdx.x;
    const int b    = bid & 7;
    const int qt   = (NQT - 1) - (bid >> 3);
    const int i0   = qt * BQ;
    const int NT   = ((qt * BQ + (BQ - 2)) >> 6) + 1;

    const int lane = tid & 63;
    const int w    = tid >> 6;
    const int rg   = w >> 1;
    const int ch   = w & 1;
    const int lr   = lane & 15;
    const int lg   = lane >> 4;

    for (int c = tid; c < BQ * 16; c += 256) {
        const int row = c >> 4, c8 = c & 15;
        const float4 f0 = *(const float4*)&q[((size_t)(b * S + i0 + row)) * D + c8 * 8];
        const float4 f1 = *(const float4*)&q[((size_t)(b * S + i0 + row)) * D + c8 * 8 + 4];
        bfv8 t;
        t[0] = (__bf16)f0.x; t[1] = (__bf16)f0.y; t[2] = (__bf16)f0.z; t[3] = (__bf16)f0.w;
        t[4] = (__bf16)f1.x; t[5] = (__bf16)f1.y; t[6] = (__bf16)f1.z; t[7] = (__bf16)f1.w;
        *(bfv8*)&qs[row][c8 * 8] = t;
    }
    __syncthreads();

    bfv8 qa[4];
#pragma unroll
    for (int ks = 0; ks < 4; ++ks)
        qa[ks] = *(const bfv8*)&qs[rg * 16 + lr][ks * 32 + lg * 8];

    int  i_r[4];
    bool bi[4];
#pragma unroll
    for (int r = 0; r < 4; ++r) {
        i_r[r] = i0 + rg * 16 + lg * 4 + r;
        bi[r]  = rep[(size_t)b * S + i_r[r]] > 0.5f;
    }

    float lsum[4] = {0.f, 0.f, 0.f, 0.f};
    for (int kt = 0; kt < NT; ++kt) {
        __syncthreads();
        for (int c = tid; c < BK * 16; c += 256) {
            const int row = c >> 4, c8 = c & 15;
            const float4 f0 = *(const float4*)&k[((size_t)(b * S + kt * BK + row)) * D + c8 * 8];
            const float4 f1 = *(const float4*)&k[((size_t)(b * S + kt * BK + row)) * D + c8 * 8 + 4];
            bfv8 t;
            t[0] = (__bf16)f0.x; t[1] = (__bf16)f0.y; t[2] = (__bf16)f0.z; t[3] = (__bf16)f0.w;
            t[4] = (__bf16)f1.x; t[5] = (__bf16)f1.y; t[6] = (__bf16)f1.z; t[7] = (__bf16)f1.w;
            *(bfv8*)&ksm[row][c8 * 8] = t;
        }
        __syncthreads();

        f32x4 acc0 = {0.f, 0.f, 0.f, 0.f}, acc1 = {0.f, 0.f, 0.f, 0.f};
#pragma unroll
        for (int ks = 0; ks < 4; ++ks) {
            const bfv8 b0 = *(const bfv8*)&ksm[ch * 32 + lr][ks * 32 + lg * 8];
            const bfv8 b1 = *(const bfv8*)&ksm[ch * 32 + 16 + lr][ks * 32 + lg * 8];
            acc0 = mfma16(qa[ks], b0, acc0);
            acc1 = mfma16(qa[ks], b1, acc1);
        }
        const int j0 = kt * BK + ch * 32 + lr;
        const int j1 = j0 + 16;
        const bool vj0 = rep[(size_t)b * S + j0] > 0.5f;
        const bool vj1 = rep[(size_t)b * S + j1] > 0.5f;
#pragma unroll
        for (int r = 0; r < 4; ++r) {
            const int i = i_r[r];
            const float p0 = (bi[r] && vj0 && (j0 < i))
                ? __expf(acc0[r] * INV_SQRT_D - (float)(i - j0)) : 0.f;
            const float p1 = (bi[r] && vj1 && (j1 < i))
                ? __expf(acc1[r] * INV_SQRT_D - (float)(i - j1)) : 0.f;
            lsum[r] += p0 + p1;
        }
    }

#pragma unroll
    for (int r = 0; r < 4; ++r) {
        lsum[r] += __shfl_xor(lsum[r], 1);
        lsum[r] += __shfl_xor(lsum[r], 2);
        lsum[r] += __shfl_xor(lsum[r], 4);
        lsum[r] += __shfl_xor(lsum[r], 8);
    }
    if (lr == 0) {
#pragma unroll
        for (int r = 0; r < 4; ++r) redsum[rg][ch][lg * 4 + r] = lsum[r];
    }
    __syncthreads();
    if (tid < BQ) {
        const float s = redsum[tid >> 4][0][tid & 15] + redsum[tid >> 4][1][tid & 15];
        dinv_lds[tid] = 1.f / (s + ((s == 0.f) ? 1.f : 0.f) + 1e-20f);
    }
    __syncthreads();

    float dinv[4];
#pragma unroll
    for (int r = 0; r < 4; ++r) dinv[r] = dinv_lds[rg * 16 + lg * 4 + r];

    f32x4 oacc[4];
#pragma unroll
    for (int nf = 0; nf < 4; ++nf) oacc[nf] = (f32x4){0.f, 0.f, 0.f, 0.f};

    for (int kt = 0; kt < NT; ++kt) {
        __syncthreads();
        for (int c = tid; c < BK * 16; c += 256) {
            const int row = c >> 4, c8 = c & 15;
            const float4 f0 = *(const float4*)&k[((size_t)(b * S + kt * BK + row)) * D + c8 * 8];
            const float4 f1 = *(const float4*)&k[((size_t)(b * S + kt * BK + row)) * D + c8 * 8 + 4];
            bfv8 t;
            t[0] = (__bf16)f0.x; t[1] = (__bf16)f0.y; t[2] = (__bf16)f0.z; t[3] = (__bf16)f0.w;
            t[4] = (__bf16)f1.x; t[5] = (__bf16)f1.y; t[6] = (__bf16)f1.z; t[7] = (__bf16)f1.w;
            *(bfv8*)&ksm[row][c8 * 8] = t;
        }
        for (int u = tid; u < 1024; u += 256) {
            const int p  = u & 31;
            const int dq = u >> 5;
            const float4 va = *(const float4*)&v[((size_t)(b * S + kt * BK + 2 * p)) * D + dq * 4];
            const float4 vb = *(const float4*)&v[((size_t)(b * S + kt * BK + 2 * p + 1)) * D + dq * 4];
            *(unsigned int*)&vsT[dq * 4 + 0][2 * p] = pack2(va.x, vb.x);
            *(unsigned int*)&vsT[dq * 4 + 1][2 * p] = pack2(va.y, vb.y);
            *(unsigned int*)&vsT[dq * 4 + 2][2 * p] = pack2(va.z, vb.z);
            *(unsigned int*)&vsT[dq * 4 + 3][2 * p] = pack2(va.w, vb.w);
        }
        __syncthreads();

        f32x4 acc0 = {0.f, 0.f, 0.f, 0.f}, acc1 = {0.f, 0.f, 0.f, 0.f};
#pragma unroll
        for (int ks = 0; ks < 4; ++ks) {
            const bfv8 b0 = *(const bfv8*)&ksm[ch * 32 + lr][ks * 32 + lg * 8];
            const bfv8 b1 = *(const bfv8*)&ksm[ch * 32 + 16 + lr][ks * 32 + lg * 8];
            acc0 = mfma16(qa[ks], b0, acc0);
            acc1 = mfma16(qa[ks], b1, acc1);
        }
        const int j0 = kt * BK + ch * 32 + lr;
        const int j1 = j0 + 16;
        const bool vj0 = rep[(size_t)b * S + j0] > 0.5f;
        const bool vj1 = rep[(size_t)b * S + j1] > 0.5f;
#pragma unroll
        for (int r = 0; r < 4; ++r) {
            const int i = i_r[r];
            const float p0 = (bi[r] && vj0 && (j0 < i))
                ? __expf(acc0[r] * INV_SQRT_D - (float)(i - j0)) * dinv[r] : 0.f;
            const float p1 = (bi[r] && vj1 && (j1 < i))
                ? __expf(acc1[r] * INV_SQRT_D - (float)(i - j1)) * dinv[r] : 0.f;
            attn[((size_t)(b * S + i)) * S + j0] = p0;
            attn[((size_t)(b * S + i)) * S + j1] = p1;
            ps[rg * 16 + lg * 4 + r][ch * 32 + lr]      = (__bf16)p0;
            ps[rg * 16 + lg * 4 + r][ch * 32 + 16 + lr] = (__bf16)p1;
        }
        __syncthreads();

#pragma unroll
        for (int ks = 0; ks < 2; ++ks) {
            const bfv8 pa = *(const bfv8*)&ps[rg * 16 + lr][ks * 32 + lg * 8];
#pragma unroll
            for (int nf = 0; nf < 4; ++nf) {
                const bfv8 vf = *(const bfv8*)&vsT[ch * 64 + nf * 16 + lr][ks * 32 + lg * 8];
                oacc[nf] = mfma16(pa, vf, oacc[nf]);
            }
        }
    }

#pragma unroll
    for (int nf = 0; nf < 4; ++nf)
#pragma unroll
        for (int r = 0; r < 4; ++r)
            out[((size_t)(b * S + i_r[r])) * D + ch * 64 + nf * 16 + lr] = oacc[nf][r];

    const int zt = NKT - NT;
    const float4 z4 = make_float4(0.f, 0.f, 0.f, 0.f);
    for (int u = tid; u < zt * 512; u += 256) {
        const int t   = u >> 9;
        const int rem = u & 511;
        const int row = rem >> 4;
        const int c4  = rem & 15;
        *(float4*)&attn[((size_t)(b * S + i0 + row)) * S + (NT + t) * BK + c4 * 4] = z4;
    }
}

extern "C" void kernel_launch(void* const* d_in, const int* in_sizes, int n_in,
                              void* d_out, int out_size, void* d_ws, size_t ws_size,
                              hipStream_t stream)
{
    const float* q   = (const float*)d_in[0];
    const float* k   = (const float*)d_in[1];
    const float* v   = (const float*)d_in[2];
    const float* rep = (const float*)d_in[3];
    float* out  = (float*)d_out;
    float* attn = out + (size_t)NBATCH * S * D;

    const size_t kb_elems = (size_t)NBATCH * S * D;
    const size_t need = kb_elems * 2 * 2;

    if (ws_size < need) {
        hipLaunchKernelGGL(attn_kernel_fb, dim3(NBATCH * NQT), dim3(256), 0, stream,
                           q, k, v, rep, out, attn);
        return;
    }

    __bf16* kb  = (__bf16*)d_ws;
    __bf16* vtb = kb + kb_elems;

    hipLaunchKernelGGL(prep_kernel, dim3(2048), dim3(256), 0, stream, k, v, kb, vtb);
    hipLaunchKernelGGL(attn_main, dim3(NBATCH * NQT), dim3(256), 0, stream,
                       q, rep, kb, vtb, out, attn);
}